// Round 10
// baseline (302.145 us; speedup 1.0000x reference)
//
#include <hip/hip_runtime.h>

#define NNODES 100000
#define NEDGES 1600000
#define IND 128
#define HIDD 128
#define OUTD 64

// bucketed CSR build: 256-node buckets, XCD-partitioned binning
#define BSHIFT 8
#define BSIZE  256
#define NBUCK  ((NNODES + BSIZE - 1) / BSIZE)        // 391
#define SLACK  4800                                  // mean 4096 + 11 sigma
#define SEG_CAP 5120
#define GRPS   8                                     // bucket-groups == XCDs
#define NBG    49                                    // max buckets per group (391 = 7*49 + 48)
#define EPJ    16384                                 // edges per slice
#define JB     ((NEDGES + EPJ - 1) / EPJ)            // 98 slices
#define BIN2B  (JB * GRPS)                           // 784 binning blocks
#define KEEP_CAP 3072                                // mean 2055 + 24 sigma
#define WTB    ((IND * HIDD + HIDD * OUTD + 255) / 256)  // 96
#define GEMMB  ((NNODES + 127) / 128)                // 782

typedef unsigned int  uint32;
typedef __attribute__((ext_vector_type(8))) short short8;
typedef __attribute__((ext_vector_type(4))) float floatx4;
typedef __attribute__((ext_vector_type(4))) unsigned int uivec4;
typedef __attribute__((ext_vector_type(4))) float fvec4;

// ---------- bf16 helpers ----------
__device__ __forceinline__ unsigned short f2bf(float f) {
    union { float f; uint32 u; } x; x.f = f;
    uint32 u = x.u;
    return (unsigned short)((u + 0x7fffu + ((u >> 16) & 1u)) >> 16);   // RNE
}
__device__ __forceinline__ float bflo(uint32 u) {
    union { uint32 i; float f; } x; x.i = u << 16; return x.f;
}
__device__ __forceinline__ float bfhi(uint32 u) {
    union { uint32 i; float f; } x; x.i = u & 0xffff0000u; return x.f;
}

// ---------- phase A: XCD-partitioned binning ----------
// Block (g = bid&7, j = bid>>3) scans edge slice j and keeps only edges whose
// bucket b = dst>>8 satisfies b%8 == g. With the measured bid%8 -> XCD round-robin,
// bucket b's staging region is then dirtied by ONE XCD's L2 only -> partial-line
// writebacks collapse (k_bin WRITE_SIZE was 57.5 MB for 6.4 MB payload, 9x amp).
// The 8x edge re-read is LLC-served (12.8 MB, all readers concurrent).
__global__ void k_bin(const int* __restrict__ src, const int* __restrict__ dst,
                      int* __restrict__ bcnt, uint32* __restrict__ staging, int e,
                      const float* __restrict__ W1, const float* __restrict__ W2,
                      unsigned short* __restrict__ wt1, unsigned short* __restrict__ wt2) {
    const int tid = threadIdx.x;
    if (blockIdx.x >= BIN2B) {
        int idx = (blockIdx.x - BIN2B) * 256 + tid;
        if (idx < IND * HIDD) {
            int k = idx / HIDD, m = idx - k * HIDD;
            wt1[m * IND + k] = f2bf(W1[idx]);
        } else {
            int j = idx - IND * HIDD;
            if (j < HIDD * OUTD) {
                int k = j / OUTD, m = j - k * OUTD;
                wt2[m * HIDD + k] = f2bf(W2[j]);
            }
        }
        return;
    }

    __shared__ int lh[NBG];
    __shared__ int lcur[NBG];
    __shared__ int nk;
    __shared__ uint32 keep[KEEP_CAP];    // 12 KB

    const int g = blockIdx.x & 7;
    const int j = blockIdx.x >> 3;

    for (int i = tid; i < NBG; i += 256) lh[i] = 0;
    if (tid == 0) nk = 0;
    __syncthreads();

    const int start = j * EPJ;
    const int end = min(start + EPJ, e);        // e % 4 == 0 -> whole int4s
    const int4* d4 = (const int4*)dst;
    const int4* s4 = (const int4*)src;

    for (int off = start + 4 * tid; off < end; off += 1024) {
        int4 dv = d4[off >> 2];
        int4 sv = s4[off >> 2];
#define PROC(DD, SS)                                                          \
        {                                                                     \
            int d = (DD), s = (SS);                                           \
            int b = d >> BSHIFT;                                              \
            if ((b & 7) == g) {                                               \
                int k = atomicAdd(&nk, 1);                                    \
                if (k < KEEP_CAP) {                                           \
                    atomicAdd(&lh[b >> 3], 1);                                \
                    keep[k] = ((uint32)(b >> 3) << 25) |                      \
                              ((uint32)(d & (BSIZE - 1)) << 17) | (uint32)s;  \
                }                                                             \
            }                                                                 \
        }
        PROC(dv.x, sv.x)
        PROC(dv.y, sv.y)
        PROC(dv.z, sv.z)
        PROC(dv.w, sv.w)
#undef PROC
    }
    __syncthreads();

    for (int i = tid; i < NBG; i += 256) {
        int b = (i << 3) | g;
        lcur[i] = (b < NBUCK && lh[i]) ? atomicAdd(&bcnt[b], lh[i]) : 0;
    }
    __syncthreads();

    const int kn = min(nk, KEEP_CAP);
    for (int k = tid; k < kn; k += 256) {
        uint32 e2 = keep[k];
        int i = (int)(e2 >> 25);
        int pos = atomicAdd(&lcur[i], 1);
        if (pos < SLACK)
            staging[(size_t)((i << 3) | g) * SLACK + pos] = e2 & 0x1FFFFFFu;
    }
}

// ---------- phase C: per-bucket CSR finalize (256 nodes/bucket, one node/thread) ----------
__global__ __launch_bounds__(256)
void k_fill3(const uint32* __restrict__ staging, const int* __restrict__ bcnt,
             int* __restrict__ row_ptr, int* __restrict__ csr_src,
             float* __restrict__ dinv, int n) {
    __shared__ int nc[BSIZE];
    __shared__ int lcur[BSIZE];
    __shared__ int red[256];
    __shared__ int wsum[4];
    __shared__ int seg[SEG_CAP];    // 20 KB
    const int b = blockIdx.x;
    const int base = b << BSHIFT;
    const int tid = threadIdx.x;

    nc[tid] = 0;

    // r0 = sum of bucket counts below b (reduction, not scan)
    int t0 = (tid < b) ? bcnt[tid] : 0;
    int t1 = (tid + 256 < b) ? bcnt[tid + 256] : 0;
    red[tid] = t0 + t1;
    __syncthreads();
    for (int off = 128; off > 0; off >>= 1) {
        if (tid < off) red[tid] += red[tid + off];
        __syncthreads();
    }
    const int r0 = red[0];

    const uint32* st = staging + (size_t)b * SLACK;
    const int cnt = bcnt[b];
    for (int i = tid; i < cnt; i += 256)
        atomicAdd(&nc[st[i] >> 17], 1);
    __syncthreads();

    // per-node exclusive offsets: wave-shuffle inclusive scan over 256
    const int lane = tid & 63;
    const int w = tid >> 6;
    int dg = nc[tid];
    int v = dg;
#pragma unroll
    for (int off = 1; off < 64; off <<= 1) {
        int t = __shfl_up(v, off);
        if (lane >= off) v += t;
    }
    if (lane == 63) wsum[w] = v;
    __syncthreads();
    if (tid == 0) {
        int a = 0;
#pragma unroll
        for (int i = 0; i < 4; i++) { int t = wsum[i]; wsum[i] = a; a += t; }
    }
    __syncthreads();
    const int inc = v + wsum[w];     // inclusive prefix
    const int ex = inc - dg;
    const int vnode = base + tid;
    if (vnode < n) {
        row_ptr[vnode] = r0 + ex;
        dinv[vnode] = rsqrtf((float)(dg + 1));
    }
    lcur[tid] = ex;
    if (b == NBUCK - 1 && tid == 255) row_ptr[n] = r0 + inc;   // inc@255 == cnt
    __syncthreads();

    for (int i = tid; i < cnt; i += 256) {
        uint32 p = st[i];
        int dl = (int)(p >> 17);
        int s  = (int)(p & 0x1FFFFu);
        int pos = atomicAdd(&lcur[dl], 1);
        if (pos < SEG_CAP) seg[pos] = s;
        else               csr_src[r0 + pos] = s;
    }
    __syncthreads();
    int lim = min(cnt, SEG_CAP);
    for (int i = tid; i < lim; i += 256) csr_src[r0 + i] = seg[i];
}

// ---------- MFMA bf16 GEMM: 128-row tiles, 512 threads (8 waves) ----------
template<int K, int M, bool ABF16>
__launch_bounds__(512)
__global__ void gemm_mfma(const void* __restrict__ Ap, const unsigned short* __restrict__ WT,
                          const float* __restrict__ dinv, unsigned short* __restrict__ C, int n) {
    constexpr int KP = K + 8;
    constexpr int NT = M / 16;
    __shared__ unsigned short Asl[128 * KP];
    __shared__ unsigned short Wsl[M * KP];

    const int tid = threadIdx.x;
    const int row0 = blockIdx.x * 128;

    {
        constexpr int SEG = (K * 2) / 16;
        const uint4* srcp = (const uint4*)WT;
        for (int idx = tid; idx < M * SEG; idx += 512) {
            int r = idx / SEG, s = idx - r * SEG;
            *(uint4*)(Wsl + r * KP + s * 8) = srcp[idx];
        }
    }
    if constexpr (ABF16) {
        constexpr int U4R = K / 8;
        const unsigned short* Ab = (const unsigned short*)Ap;
        for (int idx = tid; idx < 128 * U4R; idx += 512) {
            int r = idx / U4R, s = idx - r * U4R;
            int grow = row0 + r; if (grow >= n) grow = n - 1;
            *(uint4*)(Asl + r * KP + s * 8) = *(const uint4*)(Ab + (size_t)grow * K + s * 8);
        }
    } else {
        constexpr int F4R = K / 4;
        const float* Af = (const float*)Ap;
        for (int idx = tid; idx < 128 * F4R; idx += 512) {
            int r = idx / F4R, s = idx - r * F4R;
            int grow = row0 + r; if (grow >= n) grow = n - 1;
            float4 v = *(const float4*)(Af + (size_t)grow * K + s * 4);
            uint32 p0 = (uint32)f2bf(v.x) | ((uint32)f2bf(v.y) << 16);
            uint32 p1 = (uint32)f2bf(v.z) | ((uint32)f2bf(v.w) << 16);
            *(uint2*)(Asl + r * KP + s * 4) = make_uint2(p0, p1);
        }
    }
    __syncthreads();

    const int lane = tid & 63;
    const int wave = tid >> 6;          // 0..7 -> rows wave*16 .. wave*16+15
    const int mm = lane & 15;
    const int qq = lane >> 4;

    floatx4 acc[NT];
#pragma unroll
    for (int t = 0; t < NT; t++) acc[t] = (floatx4){0.f, 0.f, 0.f, 0.f};

#pragma unroll
    for (int kc = 0; kc < K / 32; kc++) {
        short8 a = *(const short8*)(Asl + (wave * 16 + mm) * KP + kc * 32 + qq * 8);
#pragma unroll
        for (int t = 0; t < NT; t++) {
            short8 b = *(const short8*)(Wsl + (t * 16 + mm) * KP + kc * 32 + qq * 8);
            acc[t] = __builtin_amdgcn_mfma_f32_16x16x32_bf16(a, b, acc[t], 0, 0, 0);
        }
    }

#pragma unroll
    for (int r = 0; r < 4; r++) {
        int grow = row0 + wave * 16 + qq * 4 + r;
        if (grow < n) {
            float dv = dinv[grow];
#pragma unroll
            for (int t = 0; t < NT; t++)
                C[(size_t)grow * M + t * 16 + mm] = f2bf(acc[t][r] * dv);
        }
    }
}

// ---------- FUSED layer-1 gather + (hr @ W2)*dinv ----------
__launch_bounds__(256)
__global__ void gather_gemm(const unsigned short* __restrict__ h,
                            const int* __restrict__ row_ptr,
                            const int* __restrict__ csr_src,
                            const float* __restrict__ dinv,
                            const float* __restrict__ bias1,
                            const unsigned short* __restrict__ WT2,
                            unsigned short* __restrict__ C2, int n) {
    constexpr int K  = HIDD;          // 128
    constexpr int KP = K + 8;         // 136
    constexpr int M2 = OUTD;          // 64
    __shared__ unsigned short Atl[16 * KP];     // 4.3 KB hr tile
    __shared__ unsigned short Wsl[M2 * KP];     // 17 KB W2^T

    const int tid = threadIdx.x;

    {
        constexpr int SEG = (K * 2) / 16;   // 16
        const uint4* srcp = (const uint4*)WT2;
        for (int idx = tid; idx < M2 * SEG; idx += 256) {
            int r = idx / SEG, s = idx - r * SEG;
            *(uint4*)(Wsl + r * KP + s * 8) = srcp[idx];
        }
    }

    const int g = tid >> 4;            // node within tile: 0..15
    const int l = tid & 15;            // feature slot: 0..15 (8 feats each)
    const int v0 = blockIdx.x * 16;
    const int v = v0 + g;

    uint4 pk = make_uint4(0u, 0u, 0u, 0u);
    if (v < n) {
        const float dv = dinv[v];
        float acc[8];
        {
            uint4 u = *(const uint4*)(h + (size_t)v * K + l * 8);
            acc[0] = bflo(u.x); acc[1] = bfhi(u.x);
            acc[2] = bflo(u.y); acc[3] = bfhi(u.y);
            acc[4] = bflo(u.z); acc[5] = bfhi(u.z);
            acc[6] = bflo(u.w); acc[7] = bfhi(u.w);
        }

        int j   = row_ptr[v];
        int end = row_ptr[v + 1];
        for (; j + 3 < end; j += 4) {
            int s0 = csr_src[j];
            int s1 = csr_src[j + 1];
            int s2 = csr_src[j + 2];
            int s3 = csr_src[j + 3];
            uint4 u0 = *(const uint4*)(h + (size_t)s0 * K + l * 8);
            uint4 u1 = *(const uint4*)(h + (size_t)s1 * K + l * 8);
            uint4 u2 = *(const uint4*)(h + (size_t)s2 * K + l * 8);
            uint4 u3 = *(const uint4*)(h + (size_t)s3 * K + l * 8);
            acc[0] += (bflo(u0.x) + bflo(u1.x)) + (bflo(u2.x) + bflo(u3.x));
            acc[1] += (bfhi(u0.x) + bfhi(u1.x)) + (bfhi(u2.x) + bfhi(u3.x));
            acc[2] += (bflo(u0.y) + bflo(u1.y)) + (bflo(u2.y) + bflo(u3.y));
            acc[3] += (bfhi(u0.y) + bfhi(u1.y)) + (bfhi(u2.y) + bfhi(u3.y));
            acc[4] += (bflo(u0.z) + bflo(u1.z)) + (bflo(u2.z) + bflo(u3.z));
            acc[5] += (bfhi(u0.z) + bfhi(u1.z)) + (bfhi(u2.z) + bfhi(u3.z));
            acc[6] += (bflo(u0.w) + bflo(u1.w)) + (bflo(u2.w) + bflo(u3.w));
            acc[7] += (bfhi(u0.w) + bfhi(u1.w)) + (bfhi(u2.w) + bfhi(u3.w));
        }
        for (; j < end; j++) {
            int s0 = csr_src[j];
            uint4 u0 = *(const uint4*)(h + (size_t)s0 * K + l * 8);
            acc[0] += bflo(u0.x); acc[1] += bfhi(u0.x);
            acc[2] += bflo(u0.y); acc[3] += bfhi(u0.y);
            acc[4] += bflo(u0.z); acc[5] += bfhi(u0.z);
            acc[6] += bflo(u0.w); acc[7] += bfhi(u0.w);
        }

#pragma unroll
        for (int i = 0; i < 8; i++) {
            acc[i] = fmaxf(acc[i] * dv + bias1[l * 8 + i], 0.0f);
        }
        pk.x = (uint32)f2bf(acc[0]) | ((uint32)f2bf(acc[1]) << 16);
        pk.y = (uint32)f2bf(acc[2]) | ((uint32)f2bf(acc[3]) << 16);
        pk.z = (uint32)f2bf(acc[4]) | ((uint32)f2bf(acc[5]) << 16);
        pk.w = (uint32)f2bf(acc[6]) | ((uint32)f2bf(acc[7]) << 16);
    }
    *(uint4*)(Atl + g * KP + l * 8) = pk;    // zero rows for v >= n
    __syncthreads();

    // MFMA: 16 nodes x 64 out-feats; wave wv owns column tile wv*16..wv*16+15
    const int lane = tid & 63;
    const int wv = tid >> 6;           // 0..3
    const int mm = lane & 15;
    const int qq = lane >> 4;

    floatx4 o = (floatx4){0.f, 0.f, 0.f, 0.f};
#pragma unroll
    for (int kc = 0; kc < K / 32; kc++) {
        short8 a = *(const short8*)(Atl + mm * KP + kc * 32 + qq * 8);
        short8 b = *(const short8*)(Wsl + (wv * 16 + mm) * KP + kc * 32 + qq * 8);
        o = __builtin_amdgcn_mfma_f32_16x16x32_bf16(a, b, o, 0, 0, 0);
    }

#pragma unroll
    for (int r = 0; r < 4; r++) {
        int grow = v0 + qq * 4 + r;
        if (grow < n) {
            float dv2 = dinv[grow];
            C2[(size_t)grow * M2 + wv * 16 + mm] = f2bf(o[r] * dv2);
        }
    }
}

// ---------- gather-aggregate over premultiplied bf16 table (node-major rows) ----------
template<int M, bool RELU, bool OBF16>
__launch_bounds__(256)
__global__ void gather_k(const unsigned short* __restrict__ h,
                         const int* __restrict__ row_ptr,
                         const int* __restrict__ csr_src,
                         const float* __restrict__ dinv,
                         const float* __restrict__ bias,
                         void* __restrict__ outp, int n) {
    constexpr int LPG = M / 8;
    constexpr int GPB = 256 / LPG;
    const int g = threadIdx.x / LPG;
    const int l = threadIdx.x % LPG;
    const int v = blockIdx.x * GPB + g;
    if (v >= n) return;

    const float dv = dinv[v];
    float acc[8];
    {
        uint4 u = *(const uint4*)(h + (size_t)v * M + l * 8);
        acc[0] = bflo(u.x); acc[1] = bfhi(u.x);
        acc[2] = bflo(u.y); acc[3] = bfhi(u.y);
        acc[4] = bflo(u.z); acc[5] = bfhi(u.z);
        acc[6] = bflo(u.w); acc[7] = bfhi(u.w);
    }

    int j   = row_ptr[v];
    int end = row_ptr[v + 1];
    for (; j + 3 < end; j += 4) {
        int s0 = csr_src[j];
        int s1 = csr_src[j + 1];
        int s2 = csr_src[j + 2];
        int s3 = csr_src[j + 3];
        uint4 u0 = *(const uint4*)(h + (size_t)s0 * M + l * 8);
        uint4 u1 = *(const uint4*)(h + (size_t)s1 * M + l * 8);
        uint4 u2 = *(const uint4*)(h + (size_t)s2 * M + l * 8);
        uint4 u3 = *(const uint4*)(h + (size_t)s3 * M + l * 8);
        acc[0] += (bflo(u0.x) + bflo(u1.x)) + (bflo(u2.x) + bflo(u3.x));
        acc[1] += (bfhi(u0.x) + bfhi(u1.x)) + (bfhi(u2.x) + bfhi(u3.x));
        acc[2] += (bflo(u0.y) + bflo(u1.y)) + (bflo(u2.y) + bflo(u3.y));
        acc[3] += (bfhi(u0.y) + bfhi(u1.y)) + (bfhi(u2.y) + bfhi(u3.y));
        acc[4] += (bflo(u0.z) + bflo(u1.z)) + (bflo(u2.z) + bflo(u3.z));
        acc[5] += (bfhi(u0.z) + bfhi(u1.z)) + (bfhi(u2.z) + bfhi(u3.z));
        acc[6] += (bflo(u0.w) + bflo(u1.w)) + (bflo(u2.w) + bflo(u3.w));
        acc[7] += (bfhi(u0.w) + bfhi(u1.w)) + (bfhi(u2.w) + bfhi(u3.w));
    }
    for (; j < end; j++) {
        int s0 = csr_src[j];
        uint4 u0 = *(const uint4*)(h + (size_t)s0 * M + l * 8);
        acc[0] += bflo(u0.x); acc[1] += bfhi(u0.x);
        acc[2] += bflo(u0.y); acc[3] += bfhi(u0.y);
        acc[4] += bflo(u0.z); acc[5] += bfhi(u0.z);
        acc[6] += bflo(u0.w); acc[7] += bfhi(u0.w);
    }

#pragma unroll
    for (int i = 0; i < 8; i++) {
        acc[i] = acc[i] * dv + bias[l * 8 + i];
        if (RELU) acc[i] = fmaxf(acc[i], 0.0f);
    }

    if constexpr (OBF16) {
        uivec4 p;
#pragma unroll
        for (int c = 0; c < 4; c++)
            p[c] = (uint32)f2bf(acc[2 * c]) | ((uint32)f2bf(acc[2 * c + 1]) << 16);
        __builtin_nontemporal_store(p,
            (uivec4*)((unsigned short*)outp + (size_t)v * M + l * 8));
    } else {
        float* op = (float*)outp + (size_t)v * M + l * 8;
        fvec4 a0 = {acc[0], acc[1], acc[2], acc[3]};
        fvec4 a1 = {acc[4], acc[5], acc[6], acc[7]};
        __builtin_nontemporal_store(a0, (fvec4*)op);
        __builtin_nontemporal_store(a1, (fvec4*)(op + 4));
    }
}

extern "C" void kernel_launch(void* const* d_in, const int* in_sizes, int n_in,
                              void* d_out, int out_size, void* d_ws, size_t ws_size,
                              hipStream_t stream) {
    const float* x  = (const float*)d_in[0];
    const float* W1 = (const float*)d_in[1];
    const float* b1 = (const float*)d_in[2];
    const float* W2 = (const float*)d_in[3];
    const float* b2 = (const float*)d_in[4];
    const int*   ei = (const int*)d_in[5];
    const int* src = ei;            // edge_index[0]
    const int* dst = ei + NEDGES;   // edge_index[1]
    float* out = (float*)d_out;

    // workspace layout (16B-aligned chunks):
    char* ws = (char*)d_ws;
    float*  dinv    = (float*)ws;   ws += (size_t)NNODES * 4;
    int*    row_ptr = (int*)ws;     ws += (size_t)(NNODES + 4) * 4;
    int*    bcnt    = (int*)ws;     ws += 512 * 4;
    unsigned short* wt1 = (unsigned short*)ws;  ws += (size_t)IND * HIDD * 2;
    unsigned short* wt2 = (unsigned short*)ws;  ws += (size_t)HIDD * OUTD * 2;
    int*    csr_src = (int*)ws;     ws += (size_t)NEDGES * 4;
    uint32* staging = (uint32*)ws;  ws += (size_t)NBUCK * SLACK * 4;   // 7.5 MB
    unsigned short* hbf1 = (unsigned short*)ws; ws += (size_t)NNODES * HIDD * 2;  // layer-1 bf16 table
    unsigned short* hbf2 = (unsigned short*)ws;                                    // layer-2 bf16 table

    // ---- CSR build ----
    hipMemsetAsync(bcnt, 0, 512 * 4, stream);
    k_bin<<<BIN2B + WTB, 256, 0, stream>>>(src, dst, bcnt, staging, NEDGES, W1, W2, wt1, wt2);
    k_fill3<<<NBUCK, 256, 0, stream>>>(staging, bcnt, row_ptr, csr_src, dinv, NNODES);

    // ---- layer 1 GEMM: hbf1(bf16) = (x @ W1)*dinv ----
    gemm_mfma<IND, HIDD, false><<<GEMMB, 512, 0, stream>>>(
        x, wt1, dinv, hbf1, NNODES);

    // ---- fused: gather1 (+b1, ReLU) -> @W2 -> *dinv -> hbf2(bf16) ----
    gather_gemm<<<(NNODES + 15) / 16, 256, 0, stream>>>(
        hbf1, row_ptr, csr_src, dinv, b1, wt2, hbf2, NNODES);

    // ---- layer 2 gather: out(f32) = gather(hbf2)*dv + b2 ----
    gather_k<OUTD, false, false><<<(NNODES * (OUTD / 8) + 255) / 256, 256, 0, stream>>>(
        hbf2, row_ptr, csr_src, dinv, b2, out, NNODES);
}

// Round 11
// 286.605 us; speedup vs baseline: 1.0542x; 1.0542x over previous
//
#include <hip/hip_runtime.h>

#define NNODES 100000
#define NEDGES 1600000
#define IND 128
#define HIDD 128
#define OUTD 64

// bucketed CSR build: 256-node buckets
#define BSHIFT 8
#define BSIZE  256
#define NBUCK  ((NNODES + BSIZE - 1) / BSIZE)        // 391
#define SLACK  4800                                  // mean 4096 + 11 sigma
#define SEG_CAP 5120
#define BIN_EPB 4096
#define BINB   ((NEDGES + BIN_EPB - 1) / BIN_EPB)    // 391
#define GEMMB  ((NNODES + 127) / 128)                // 782
#define WT2B   ((HIDD * OUTD + 511) / 512)           // 16

typedef unsigned int  uint32;
typedef __attribute__((ext_vector_type(8))) short short8;
typedef __attribute__((ext_vector_type(4))) float floatx4;
typedef __attribute__((ext_vector_type(4))) unsigned int uivec4;
typedef __attribute__((ext_vector_type(4))) float fvec4;

// ---------- bf16 helpers ----------
__device__ __forceinline__ unsigned short f2bf(float f) {
    union { float f; uint32 u; } x; x.f = f;
    uint32 u = x.u;
    return (unsigned short)((u + 0x7fffu + ((u >> 16) & 1u)) >> 16);   // RNE
}
__device__ __forceinline__ float bflo(uint32 u) {
    union { uint32 i; float f; } x; x.i = u << 16; return x.f;
}
__device__ __forceinline__ float bfhi(uint32 u) {
    union { uint32 i; float f; } x; x.i = u & 0xffff0000u; return x.f;
}

// ---------- merged dispatch 1: edge binning + layer-1 GEMM (no dinv) + W2 transpose ----------
// blocks [0, BINB): register-held binning (round-9 proven form, 512 threads).
// blocks [BINB, BINB+GEMMB): C1[n x 128](bf16, UNSCALED) = x @ W1. W1 transposed in-kernel.
//   (gemm no longer needs dinv -> zero dependency on the CSR build -> rides under
//    the latency-bound binning blocks for free.)
// blocks [BINB+GEMMB, +WT2B): W2 transpose for the later gather_gemm.
__launch_bounds__(512)
__global__ void k_bin_gemm(const int* __restrict__ src, const int* __restrict__ dst,
                           int* __restrict__ bcnt, uint32* __restrict__ staging, int e,
                           const float* __restrict__ x, const float* __restrict__ W1,
                           const float* __restrict__ W2, unsigned short* __restrict__ wt2,
                           unsigned short* __restrict__ C, int n) {
    constexpr int K = IND;            // 128
    constexpr int KP = K + 8;         // 136
    constexpr int M = HIDD;           // 128
    constexpr int NT = M / 16;
    __shared__ __align__(16) char smem[2 * 128 * KP * 2];   // 69632 B

    const int tid = threadIdx.x;
    const int bid = blockIdx.x;

    if (bid < BINB) {
        int* lh   = (int*)smem;
        int* lcur = lh + NBUCK;
        for (int i = tid; i < NBUCK; i += 512) lh[i] = 0;
        __syncthreads();

        const int start = bid * BIN_EPB;
        const int4* d4 = (const int4*)dst;
        const int4* s4 = (const int4*)src;

        int4 dv[2], sv[2];
        bool val[2];
#pragma unroll
        for (int k = 0; k < 2; k++) {
            int off = start + 4 * (k * 512 + tid);
            val[k] = off < e;
            if (val[k]) { dv[k] = d4[off >> 2]; sv[k] = s4[off >> 2]; }
        }

#pragma unroll
        for (int k = 0; k < 2; k++) {
            if (val[k]) {
                atomicAdd(&lh[dv[k].x >> BSHIFT], 1);
                atomicAdd(&lh[dv[k].y >> BSHIFT], 1);
                atomicAdd(&lh[dv[k].z >> BSHIFT], 1);
                atomicAdd(&lh[dv[k].w >> BSHIFT], 1);
            }
        }
        __syncthreads();

        for (int i = tid; i < NBUCK; i += 512)
            lcur[i] = lh[i] ? atomicAdd(&bcnt[i], lh[i]) : 0;
        __syncthreads();

#pragma unroll
        for (int k = 0; k < 2; k++) {
            if (val[k]) {
                int d, s, b, pos;
                d = dv[k].x; s = sv[k].x; b = d >> BSHIFT;
                pos = atomicAdd(&lcur[b], 1);
                if (pos < SLACK) staging[(size_t)b * SLACK + pos] = ((uint32)(d & (BSIZE - 1)) << 17) | (uint32)s;
                d = dv[k].y; s = sv[k].y; b = d >> BSHIFT;
                pos = atomicAdd(&lcur[b], 1);
                if (pos < SLACK) staging[(size_t)b * SLACK + pos] = ((uint32)(d & (BSIZE - 1)) << 17) | (uint32)s;
                d = dv[k].z; s = sv[k].z; b = d >> BSHIFT;
                pos = atomicAdd(&lcur[b], 1);
                if (pos < SLACK) staging[(size_t)b * SLACK + pos] = ((uint32)(d & (BSIZE - 1)) << 17) | (uint32)s;
                d = dv[k].w; s = sv[k].w; b = d >> BSHIFT;
                pos = atomicAdd(&lcur[b], 1);
                if (pos < SLACK) staging[(size_t)b * SLACK + pos] = ((uint32)(d & (BSIZE - 1)) << 17) | (uint32)s;
            }
        }
        return;
    }

    if (bid >= BINB + GEMMB) {
        // W2 transpose
        int idx = (bid - BINB - GEMMB) * 512 + tid;
        if (idx < HIDD * OUTD) {
            int k = idx / OUTD, m = idx - k * OUTD;
            wt2[m * HIDD + k] = f2bf(W2[idx]);
        }
        return;
    }

    // ---- layer-1 GEMM branch: C = bf16(x @ W1), unscaled ----
    unsigned short* Asl = (unsigned short*)smem;       // 128 x KP
    unsigned short* Wsl = Asl + 128 * KP;              // 128 x KP

    const int row0 = (bid - BINB) * 128;

    // W1 in-kernel transpose-stage: W1[k][m] (row-major) -> Wsl[m*KP + k]
    for (int idx = tid; idx < 128 * 128; idx += 512) {
        int k = idx >> 7, m = idx & 127;               // coalesced read over m
        Wsl[m * KP + k] = f2bf(W1[idx]);
    }
    {
        constexpr int F4R = K / 4;
        for (int idx = tid; idx < 128 * F4R; idx += 512) {
            int r = idx / F4R, s = idx - r * F4R;
            int grow = row0 + r; if (grow >= n) grow = n - 1;
            float4 v = *(const float4*)(x + (size_t)grow * K + s * 4);
            uint32 p0 = (uint32)f2bf(v.x) | ((uint32)f2bf(v.y) << 16);
            uint32 p1 = (uint32)f2bf(v.z) | ((uint32)f2bf(v.w) << 16);
            *(uint2*)(Asl + r * KP + s * 4) = make_uint2(p0, p1);
        }
    }
    __syncthreads();

    const int lane = tid & 63;
    const int wave = tid >> 6;
    const int mm = lane & 15;
    const int qq = lane >> 4;

    floatx4 acc[NT];
#pragma unroll
    for (int t = 0; t < NT; t++) acc[t] = (floatx4){0.f, 0.f, 0.f, 0.f};

#pragma unroll
    for (int kc = 0; kc < K / 32; kc++) {
        short8 a = *(const short8*)(Asl + (wave * 16 + mm) * KP + kc * 32 + qq * 8);
#pragma unroll
        for (int t = 0; t < NT; t++) {
            short8 b = *(const short8*)(Wsl + (t * 16 + mm) * KP + kc * 32 + qq * 8);
            acc[t] = __builtin_amdgcn_mfma_f32_16x16x32_bf16(a, b, acc[t], 0, 0, 0);
        }
    }

#pragma unroll
    for (int r = 0; r < 4; r++) {
        int grow = row0 + wave * 16 + qq * 4 + r;
        if (grow < n) {
#pragma unroll
            for (int t = 0; t < NT; t++)
                C[(size_t)grow * M + t * 16 + mm] = f2bf(acc[t][r]);
        }
    }
}

// ---------- phase C: per-bucket CSR finalize (256 nodes/bucket, one node/thread) ----------
__global__ __launch_bounds__(256)
void k_fill3(const uint32* __restrict__ staging, const int* __restrict__ bcnt,
             int* __restrict__ row_ptr, int* __restrict__ csr_src,
             float* __restrict__ dinv, int n) {
    __shared__ int nc[BSIZE];
    __shared__ int lcur[BSIZE];
    __shared__ int red[256];
    __shared__ int wsum[4];
    __shared__ int seg[SEG_CAP];    // 20 KB
    const int b = blockIdx.x;
    const int base = b << BSHIFT;
    const int tid = threadIdx.x;

    nc[tid] = 0;

    // r0 = sum of bucket counts below b (reduction, not scan)
    int t0 = (tid < b) ? bcnt[tid] : 0;
    int t1 = (tid + 256 < b) ? bcnt[tid + 256] : 0;
    red[tid] = t0 + t1;
    __syncthreads();
    for (int off = 128; off > 0; off >>= 1) {
        if (tid < off) red[tid] += red[tid + off];
        __syncthreads();
    }
    const int r0 = red[0];

    const uint32* st = staging + (size_t)b * SLACK;
    const int cnt = bcnt[b];
    for (int i = tid; i < cnt; i += 256)
        atomicAdd(&nc[st[i] >> 17], 1);
    __syncthreads();

    // per-node exclusive offsets: wave-shuffle inclusive scan over 256
    const int lane = tid & 63;
    const int w = tid >> 6;
    int dg = nc[tid];
    int v = dg;
#pragma unroll
    for (int off = 1; off < 64; off <<= 1) {
        int t = __shfl_up(v, off);
        if (lane >= off) v += t;
    }
    if (lane == 63) wsum[w] = v;
    __syncthreads();
    if (tid == 0) {
        int a = 0;
#pragma unroll
        for (int i = 0; i < 4; i++) { int t = wsum[i]; wsum[i] = a; a += t; }
    }
    __syncthreads();
    const int inc = v + wsum[w];     // inclusive prefix
    const int ex = inc - dg;
    const int vnode = base + tid;
    if (vnode < n) {
        row_ptr[vnode] = r0 + ex;
        dinv[vnode] = rsqrtf((float)(dg + 1));
    }
    lcur[tid] = ex;
    if (b == NBUCK - 1 && tid == 255) row_ptr[n] = r0 + inc;   // inc@255 == cnt
    __syncthreads();

    for (int i = tid; i < cnt; i += 256) {
        uint32 p = st[i];
        int dl = (int)(p >> 17);
        int s  = (int)(p & 0x1FFFFu);
        int pos = atomicAdd(&lcur[dl], 1);
        if (pos < SEG_CAP) seg[pos] = s;
        else               csr_src[r0 + pos] = s;
    }
    __syncthreads();
    int lim = min(cnt, SEG_CAP);
    for (int i = tid; i < lim; i += 256) csr_src[r0 + i] = seg[i];
}

// ---------- FUSED layer-1 gather (dinv applied in-loop) + (hr @ W2)*dinv ----------
// h is UNSCALED bf16(x@W1); per-edge source weight dinv[s] comes from the 400 KB
// L2-resident dinv array (broadcast 4 B load, ~2% of the 256 B row read).
__launch_bounds__(256)
__global__ void gather_gemm(const unsigned short* __restrict__ h,
                            const int* __restrict__ row_ptr,
                            const int* __restrict__ csr_src,
                            const float* __restrict__ dinv,
                            const float* __restrict__ bias1,
                            const unsigned short* __restrict__ WT2,
                            unsigned short* __restrict__ C2, int n) {
    constexpr int K  = HIDD;          // 128
    constexpr int KP = K + 8;         // 136
    constexpr int M2 = OUTD;          // 64
    __shared__ unsigned short Atl[16 * KP];     // 4.3 KB hr tile
    __shared__ unsigned short Wsl[M2 * KP];     // 17 KB W2^T

    const int tid = threadIdx.x;

    {
        constexpr int SEG = (K * 2) / 16;   // 16
        const uint4* srcp = (const uint4*)WT2;
        for (int idx = tid; idx < M2 * SEG; idx += 256) {
            int r = idx / SEG, s = idx - r * SEG;
            *(uint4*)(Wsl + r * KP + s * 8) = srcp[idx];
        }
    }

    const int g = tid >> 4;            // node within tile: 0..15
    const int l = tid & 15;            // feature slot: 0..15 (8 feats each)
    const int v0 = blockIdx.x * 16;
    const int v = v0 + g;

    uint4 pk = make_uint4(0u, 0u, 0u, 0u);
    if (v < n) {
        const float dv = dinv[v];
        float acc[8];
        {   // self-loop term: dinv[v] * h[v]
            uint4 u = *(const uint4*)(h + (size_t)v * K + l * 8);
            acc[0] = dv * bflo(u.x); acc[1] = dv * bfhi(u.x);
            acc[2] = dv * bflo(u.y); acc[3] = dv * bfhi(u.y);
            acc[4] = dv * bflo(u.z); acc[5] = dv * bfhi(u.z);
            acc[6] = dv * bflo(u.w); acc[7] = dv * bfhi(u.w);
        }

        int j   = row_ptr[v];
        int end = row_ptr[v + 1];
        for (; j + 3 < end; j += 4) {
            int s0 = csr_src[j];
            int s1 = csr_src[j + 1];
            int s2 = csr_src[j + 2];
            int s3 = csr_src[j + 3];
            float q0 = dinv[s0], q1 = dinv[s1], q2 = dinv[s2], q3 = dinv[s3];
            uint4 u0 = *(const uint4*)(h + (size_t)s0 * K + l * 8);
            uint4 u1 = *(const uint4*)(h + (size_t)s1 * K + l * 8);
            uint4 u2 = *(const uint4*)(h + (size_t)s2 * K + l * 8);
            uint4 u3 = *(const uint4*)(h + (size_t)s3 * K + l * 8);
            acc[0] += (q0 * bflo(u0.x) + q1 * bflo(u1.x)) + (q2 * bflo(u2.x) + q3 * bflo(u3.x));
            acc[1] += (q0 * bfhi(u0.x) + q1 * bfhi(u1.x)) + (q2 * bfhi(u2.x) + q3 * bfhi(u3.x));
            acc[2] += (q0 * bflo(u0.y) + q1 * bflo(u1.y)) + (q2 * bflo(u2.y) + q3 * bflo(u3.y));
            acc[3] += (q0 * bfhi(u0.y) + q1 * bfhi(u1.y)) + (q2 * bfhi(u2.y) + q3 * bfhi(u3.y));
            acc[4] += (q0 * bflo(u0.z) + q1 * bflo(u1.z)) + (q2 * bflo(u2.z) + q3 * bflo(u3.z));
            acc[5] += (q0 * bfhi(u0.z) + q1 * bfhi(u1.z)) + (q2 * bfhi(u2.z) + q3 * bfhi(u3.z));
            acc[6] += (q0 * bflo(u0.w) + q1 * bflo(u1.w)) + (q2 * bflo(u2.w) + q3 * bflo(u3.w));
            acc[7] += (q0 * bfhi(u0.w) + q1 * bfhi(u1.w)) + (q2 * bfhi(u2.w) + q3 * bfhi(u3.w));
        }
        for (; j < end; j++) {
            int s0 = csr_src[j];
            float q0 = dinv[s0];
            uint4 u0 = *(const uint4*)(h + (size_t)s0 * K + l * 8);
            acc[0] += q0 * bflo(u0.x); acc[1] += q0 * bfhi(u0.x);
            acc[2] += q0 * bflo(u0.y); acc[3] += q0 * bfhi(u0.y);
            acc[4] += q0 * bflo(u0.z); acc[5] += q0 * bfhi(u0.z);
            acc[6] += q0 * bflo(u0.w); acc[7] += q0 * bfhi(u0.w);
        }

#pragma unroll
        for (int i = 0; i < 8; i++) {
            acc[i] = fmaxf(acc[i] * dv + bias1[l * 8 + i], 0.0f);
        }
        pk.x = (uint32)f2bf(acc[0]) | ((uint32)f2bf(acc[1]) << 16);
        pk.y = (uint32)f2bf(acc[2]) | ((uint32)f2bf(acc[3]) << 16);
        pk.z = (uint32)f2bf(acc[4]) | ((uint32)f2bf(acc[5]) << 16);
        pk.w = (uint32)f2bf(acc[6]) | ((uint32)f2bf(acc[7]) << 16);
    }
    *(uint4*)(Atl + g * KP + l * 8) = pk;    // zero rows for v >= n
    __syncthreads();

    // MFMA: 16 nodes x 64 out-feats; wave wv owns column tile wv*16..wv*16+15
    const int lane = tid & 63;
    const int wv = tid >> 6;           // 0..3
    const int mm = lane & 15;
    const int qq = lane >> 4;

    floatx4 o = (floatx4){0.f, 0.f, 0.f, 0.f};
#pragma unroll
    for (int kc = 0; kc < K / 32; kc++) {
        short8 a = *(const short8*)(Atl + mm * KP + kc * 32 + qq * 8);
        short8 b = *(const short8*)(Wsl + (wv * 16 + mm) * KP + kc * 32 + qq * 8);
        o = __builtin_amdgcn_mfma_f32_16x16x32_bf16(a, b, o, 0, 0, 0);
    }

    // layer-2 table stays premultiplied by dinv (available now) -> gather_k unchanged
#pragma unroll
    for (int r = 0; r < 4; r++) {
        int grow = v0 + qq * 4 + r;
        if (grow < n) {
            float dv2 = dinv[grow];
            C2[(size_t)grow * M2 + wv * 16 + mm] = f2bf(o[r] * dv2);
        }
    }
}

// ---------- gather-aggregate over premultiplied bf16 table (node-major rows) ----------
template<int M, bool RELU, bool OBF16>
__launch_bounds__(256)
__global__ void gather_k(const unsigned short* __restrict__ h,
                         const int* __restrict__ row_ptr,
                         const int* __restrict__ csr_src,
                         const float* __restrict__ dinv,
                         const float* __restrict__ bias,
                         void* __restrict__ outp, int n) {
    constexpr int LPG = M / 8;
    constexpr int GPB = 256 / LPG;
    const int g = threadIdx.x / LPG;
    const int l = threadIdx.x % LPG;
    const int v = blockIdx.x * GPB + g;
    if (v >= n) return;

    const float dv = dinv[v];
    float acc[8];
    {
        uint4 u = *(const uint4*)(h + (size_t)v * M + l * 8);
        acc[0] = bflo(u.x); acc[1] = bfhi(u.x);
        acc[2] = bflo(u.y); acc[3] = bfhi(u.y);
        acc[4] = bflo(u.z); acc[5] = bfhi(u.z);
        acc[6] = bflo(u.w); acc[7] = bfhi(u.w);
    }

    int j   = row_ptr[v];
    int end = row_ptr[v + 1];
    for (; j + 3 < end; j += 4) {
        int s0 = csr_src[j];
        int s1 = csr_src[j + 1];
        int s2 = csr_src[j + 2];
        int s3 = csr_src[j + 3];
        uint4 u0 = *(const uint4*)(h + (size_t)s0 * M + l * 8);
        uint4 u1 = *(const uint4*)(h + (size_t)s1 * M + l * 8);
        uint4 u2 = *(const uint4*)(h + (size_t)s2 * M + l * 8);
        uint4 u3 = *(const uint4*)(h + (size_t)s3 * M + l * 8);
        acc[0] += (bflo(u0.x) + bflo(u1.x)) + (bflo(u2.x) + bflo(u3.x));
        acc[1] += (bfhi(u0.x) + bfhi(u1.x)) + (bfhi(u2.x) + bfhi(u3.x));
        acc[2] += (bflo(u0.y) + bflo(u1.y)) + (bflo(u2.y) + bflo(u3.y));
        acc[3] += (bfhi(u0.y) + bfhi(u1.y)) + (bfhi(u2.y) + bfhi(u3.y));
        acc[4] += (bflo(u0.z) + bflo(u1.z)) + (bflo(u2.z) + bflo(u3.z));
        acc[5] += (bfhi(u0.z) + bfhi(u1.z)) + (bfhi(u2.z) + bfhi(u3.z));
        acc[6] += (bflo(u0.w) + bflo(u1.w)) + (bflo(u2.w) + bflo(u3.w));
        acc[7] += (bfhi(u0.w) + bfhi(u1.w)) + (bfhi(u2.w) + bfhi(u3.w));
    }
    for (; j < end; j++) {
        int s0 = csr_src[j];
        uint4 u0 = *(const uint4*)(h + (size_t)s0 * M + l * 8);
        acc[0] += bflo(u0.x); acc[1] += bfhi(u0.x);
        acc[2] += bflo(u0.y); acc[3] += bfhi(u0.y);
        acc[4] += bflo(u0.z); acc[5] += bfhi(u0.z);
        acc[6] += bflo(u0.w); acc[7] += bfhi(u0.w);
    }

#pragma unroll
    for (int i = 0; i < 8; i++) {
        acc[i] = acc[i] * dv + bias[l * 8 + i];
        if (RELU) acc[i] = fmaxf(acc[i], 0.0f);
    }

    if constexpr (OBF16) {
        uivec4 p;
#pragma unroll
        for (int c = 0; c < 4; c++)
            p[c] = (uint32)f2bf(acc[2 * c]) | ((uint32)f2bf(acc[2 * c + 1]) << 16);
        __builtin_nontemporal_store(p,
            (uivec4*)((unsigned short*)outp + (size_t)v * M + l * 8));
    } else {
        float* op = (float*)outp + (size_t)v * M + l * 8;
        fvec4 a0 = {acc[0], acc[1], acc[2], acc[3]};
        fvec4 a1 = {acc[4], acc[5], acc[6], acc[7]};
        __builtin_nontemporal_store(a0, (fvec4*)op);
        __builtin_nontemporal_store(a1, (fvec4*)(op + 4));
    }
}

extern "C" void kernel_launch(void* const* d_in, const int* in_sizes, int n_in,
                              void* d_out, int out_size, void* d_ws, size_t ws_size,
                              hipStream_t stream) {
    const float* x  = (const float*)d_in[0];
    const float* W1 = (const float*)d_in[1];
    const float* b1 = (const float*)d_in[2];
    const float* W2 = (const float*)d_in[3];
    const float* b2 = (const float*)d_in[4];
    const int*   ei = (const int*)d_in[5];
    const int* src = ei;            // edge_index[0]
    const int* dst = ei + NEDGES;   // edge_index[1]
    float* out = (float*)d_out;

    // workspace layout (16B-aligned chunks):
    char* ws = (char*)d_ws;
    float*  dinv    = (float*)ws;   ws += (size_t)NNODES * 4;
    int*    row_ptr = (int*)ws;     ws += (size_t)(NNODES + 4) * 4;
    int*    bcnt    = (int*)ws;     ws += 512 * 4;
    unsigned short* wt2 = (unsigned short*)ws;  ws += (size_t)HIDD * OUTD * 2;
    int*    csr_src = (int*)ws;     ws += (size_t)NEDGES * 4;
    uint32* staging = (uint32*)ws;  ws += (size_t)NBUCK * SLACK * 4;   // 7.5 MB
    unsigned short* hbf1 = (unsigned short*)ws; ws += (size_t)NNODES * HIDD * 2;  // layer-1 bf16 table (unscaled)
    unsigned short* hbf2 = (unsigned short*)ws;                                    // layer-2 bf16 table (premult)

    // ---- merged: binning + layer-1 GEMM + W2 transpose (all independent) ----
    hipMemsetAsync(bcnt, 0, 512 * 4, stream);
    k_bin_gemm<<<BINB + GEMMB + WT2B, 512, 0, stream>>>(
        src, dst, bcnt, staging, NEDGES, x, W1, W2, wt2, hbf1, NNODES);

    // ---- CSR finalize -> row_ptr / csr_src / dinv ----
    k_fill3<<<NBUCK, 256, 0, stream>>>(staging, bcnt, row_ptr, csr_src, dinv, NNODES);

    // ---- fused: gather1 (dinv-in-loop, +b1, ReLU) -> @W2 -> *dinv -> hbf2(bf16) ----
    gather_gemm<<<(NNODES + 15) / 16, 256, 0, stream>>>(
        hbf1, row_ptr, csr_src, dinv, b1, wt2, hbf2, NNODES);

    // ---- layer 2 gather: out(f32) = gather(hbf2)*dv + b2 ----
    gather_k<OUTD, false, false><<<(NNODES * (OUTD / 8) + 255) / 256, 256, 0, stream>>>(
        hbf2, row_ptr, csr_src, dinv, b2, out, NNODES);
}

// Round 12
// 279.600 us; speedup vs baseline: 1.0806x; 1.0251x over previous
//
#include <hip/hip_runtime.h>

#define NNODES 100000
#define NEDGES 1600000
#define IND 128
#define HIDD 128
#define OUTD 64

// bucketed CSR build: 256-node buckets
#define BSHIFT 8
#define BSIZE  256
#define NBUCK  ((NNODES + BSIZE - 1) / BSIZE)        // 391
#define SLACK  4800                                  // mean 4092 + 11 sigma
#define SEG_CAP 5120
#define BIN_EPB 8192
#define BINB   ((NEDGES + BIN_EPB - 1) / BIN_EPB)    // 196
#define GEMMB  ((NNODES + 127) / 128)                // 782
#define WT2B   ((HIDD * OUTD + 511) / 512)           // 16

typedef unsigned int  uint32;
typedef __attribute__((ext_vector_type(8))) short short8;
typedef __attribute__((ext_vector_type(4))) float floatx4;
typedef __attribute__((ext_vector_type(4))) unsigned int uivec4;
typedef __attribute__((ext_vector_type(4))) float fvec4;

// ---------- bf16 helpers ----------
__device__ __forceinline__ unsigned short f2bf(float f) {
    union { float f; uint32 u; } x; x.f = f;
    uint32 u = x.u;
    return (unsigned short)((u + 0x7fffu + ((u >> 16) & 1u)) >> 16);   // RNE
}
__device__ __forceinline__ float bflo(uint32 u) {
    union { uint32 i; float f; } x; x.i = u << 16; return x.f;
}
__device__ __forceinline__ float bfhi(uint32 u) {
    union { uint32 i; float f; } x; x.i = u & 0xffff0000u; return x.f;
}

// ---------- merged dispatch 1: edge binning + layer-1 GEMM (no dinv) + W2 transpose ----------
// blocks [0, BINB): binning, 512 threads x 16 register-held edges (max ILP in the
//   latency-chained {LDS-atomic -> store} scatter; 196 blocks halve the per-bucket
//   global reservation chain vs 391 and double staging run length to ~21 entries).
// blocks [BINB, BINB+GEMMB): C1[n x 128](bf16, UNSCALED) = x @ W1 (no CSR dependency,
//   rides under the latency-bound binning blocks).
// blocks [BINB+GEMMB, +WT2B): W2 transpose.
__launch_bounds__(512)
__global__ void k_bin_gemm(const int* __restrict__ src, const int* __restrict__ dst,
                           int* __restrict__ bcnt, uint32* __restrict__ staging, int e,
                           const float* __restrict__ x, const float* __restrict__ W1,
                           const float* __restrict__ W2, unsigned short* __restrict__ wt2,
                           unsigned short* __restrict__ C, int n) {
    constexpr int K = IND;            // 128
    constexpr int KP = K + 8;         // 136
    constexpr int M = HIDD;           // 128
    constexpr int NT = M / 16;
    __shared__ __align__(16) char smem[2 * 128 * KP * 2];   // 69632 B

    const int tid = threadIdx.x;
    const int bid = blockIdx.x;

    if (bid < BINB) {
        int* lh   = (int*)smem;
        int* lcur = lh + NBUCK;
        for (int i = tid; i < NBUCK; i += 512) lh[i] = 0;
        __syncthreads();

        const int start = bid * BIN_EPB;
        const int4* d4 = (const int4*)dst;
        const int4* s4 = (const int4*)src;

        int4 dv[4], sv[4];
        bool val[4];
#pragma unroll
        for (int k = 0; k < 4; k++) {
            int off = start + 4 * (k * 512 + tid);   // e % 4 == 0: whole int4 valid or none
            val[k] = off < e;
            if (val[k]) { dv[k] = d4[off >> 2]; sv[k] = s4[off >> 2]; }
        }

#pragma unroll
        for (int k = 0; k < 4; k++) {
            if (val[k]) {
                atomicAdd(&lh[dv[k].x >> BSHIFT], 1);
                atomicAdd(&lh[dv[k].y >> BSHIFT], 1);
                atomicAdd(&lh[dv[k].z >> BSHIFT], 1);
                atomicAdd(&lh[dv[k].w >> BSHIFT], 1);
            }
        }
        __syncthreads();

        for (int i = tid; i < NBUCK; i += 512)
            lcur[i] = lh[i] ? atomicAdd(&bcnt[i], lh[i]) : 0;
        __syncthreads();

#pragma unroll
        for (int k = 0; k < 4; k++) {
            if (val[k]) {
                int d, s, b, pos;
                d = dv[k].x; s = sv[k].x; b = d >> BSHIFT;
                pos = atomicAdd(&lcur[b], 1);
                if (pos < SLACK) staging[(size_t)b * SLACK + pos] = ((uint32)(d & (BSIZE - 1)) << 17) | (uint32)s;
                d = dv[k].y; s = sv[k].y; b = d >> BSHIFT;
                pos = atomicAdd(&lcur[b], 1);
                if (pos < SLACK) staging[(size_t)b * SLACK + pos] = ((uint32)(d & (BSIZE - 1)) << 17) | (uint32)s;
                d = dv[k].z; s = sv[k].z; b = d >> BSHIFT;
                pos = atomicAdd(&lcur[b], 1);
                if (pos < SLACK) staging[(size_t)b * SLACK + pos] = ((uint32)(d & (BSIZE - 1)) << 17) | (uint32)s;
                d = dv[k].w; s = sv[k].w; b = d >> BSHIFT;
                pos = atomicAdd(&lcur[b], 1);
                if (pos < SLACK) staging[(size_t)b * SLACK + pos] = ((uint32)(d & (BSIZE - 1)) << 17) | (uint32)s;
            }
        }
        return;
    }

    if (bid >= BINB + GEMMB) {
        // W2 transpose
        int idx = (bid - BINB - GEMMB) * 512 + tid;
        if (idx < HIDD * OUTD) {
            int k = idx / OUTD, m = idx - k * OUTD;
            wt2[m * HIDD + k] = f2bf(W2[idx]);
        }
        return;
    }

    // ---- layer-1 GEMM branch: C = bf16(x @ W1), unscaled ----
    unsigned short* Asl = (unsigned short*)smem;       // 128 x KP
    unsigned short* Wsl = Asl + 128 * KP;              // 128 x KP

    const int row0 = (bid - BINB) * 128;

    // W1 in-kernel transpose-stage: W1[k][m] (row-major) -> Wsl[m*KP + k]
    for (int idx = tid; idx < 128 * 128; idx += 512) {
        int k = idx >> 7, m = idx & 127;               // coalesced read over m
        Wsl[m * KP + k] = f2bf(W1[idx]);
    }
    {
        constexpr int F4R = K / 4;
        for (int idx = tid; idx < 128 * F4R; idx += 512) {
            int r = idx / F4R, s = idx - r * F4R;
            int grow = row0 + r; if (grow >= n) grow = n - 1;
            float4 v = *(const float4*)(x + (size_t)grow * K + s * 4);
            uint32 p0 = (uint32)f2bf(v.x) | ((uint32)f2bf(v.y) << 16);
            uint32 p1 = (uint32)f2bf(v.z) | ((uint32)f2bf(v.w) << 16);
            *(uint2*)(Asl + r * KP + s * 4) = make_uint2(p0, p1);
        }
    }
    __syncthreads();

    const int lane = tid & 63;
    const int wave = tid >> 6;
    const int mm = lane & 15;
    const int qq = lane >> 4;

    floatx4 acc[NT];
#pragma unroll
    for (int t = 0; t < NT; t++) acc[t] = (floatx4){0.f, 0.f, 0.f, 0.f};

#pragma unroll
    for (int kc = 0; kc < K / 32; kc++) {
        short8 a = *(const short8*)(Asl + (wave * 16 + mm) * KP + kc * 32 + qq * 8);
#pragma unroll
        for (int t = 0; t < NT; t++) {
            short8 b = *(const short8*)(Wsl + (t * 16 + mm) * KP + kc * 32 + qq * 8);
            acc[t] = __builtin_amdgcn_mfma_f32_16x16x32_bf16(a, b, acc[t], 0, 0, 0);
        }
    }

#pragma unroll
    for (int r = 0; r < 4; r++) {
        int grow = row0 + wave * 16 + qq * 4 + r;
        if (grow < n) {
#pragma unroll
            for (int t = 0; t < NT; t++)
                C[(size_t)grow * M + t * 16 + mm] = f2bf(acc[t][r]);
        }
    }
}

// ---------- phase C: per-bucket CSR finalize (256 nodes/bucket, one node/thread) ----------
__global__ __launch_bounds__(256)
void k_fill3(const uint32* __restrict__ staging, const int* __restrict__ bcnt,
             int* __restrict__ row_ptr, int* __restrict__ csr_src,
             float* __restrict__ dinv, int n) {
    __shared__ int nc[BSIZE];
    __shared__ int lcur[BSIZE];
    __shared__ int red[256];
    __shared__ int wsum[4];
    __shared__ int seg[SEG_CAP];    // 20 KB
    const int b = blockIdx.x;
    const int base = b << BSHIFT;
    const int tid = threadIdx.x;

    nc[tid] = 0;

    // r0 = sum of bucket counts below b (reduction, not scan)
    int t0 = (tid < b) ? bcnt[tid] : 0;
    int t1 = (tid + 256 < b) ? bcnt[tid + 256] : 0;
    red[tid] = t0 + t1;
    __syncthreads();
    for (int off = 128; off > 0; off >>= 1) {
        if (tid < off) red[tid] += red[tid + off];
        __syncthreads();
    }
    const int r0 = red[0];

    const uint32* st = staging + (size_t)b * SLACK;
    const int cnt = bcnt[b];
    for (int i = tid; i < cnt; i += 256)
        atomicAdd(&nc[st[i] >> 17], 1);
    __syncthreads();

    // per-node exclusive offsets: wave-shuffle inclusive scan over 256
    const int lane = tid & 63;
    const int w = tid >> 6;
    int dg = nc[tid];
    int v = dg;
#pragma unroll
    for (int off = 1; off < 64; off <<= 1) {
        int t = __shfl_up(v, off);
        if (lane >= off) v += t;
    }
    if (lane == 63) wsum[w] = v;
    __syncthreads();
    if (tid == 0) {
        int a = 0;
#pragma unroll
        for (int i = 0; i < 4; i++) { int t = wsum[i]; wsum[i] = a; a += t; }
    }
    __syncthreads();
    const int inc = v + wsum[w];     // inclusive prefix
    const int ex = inc - dg;
    const int vnode = base + tid;
    if (vnode < n) {
        row_ptr[vnode] = r0 + ex;
        dinv[vnode] = rsqrtf((float)(dg + 1));
    }
    lcur[tid] = ex;
    if (b == NBUCK - 1 && tid == 255) row_ptr[n] = r0 + inc;   // inc@255 == cnt
    __syncthreads();

    for (int i = tid; i < cnt; i += 256) {
        uint32 p = st[i];
        int dl = (int)(p >> 17);
        int s  = (int)(p & 0x1FFFFu);
        int pos = atomicAdd(&lcur[dl], 1);
        if (pos < SEG_CAP) seg[pos] = s;
        else               csr_src[r0 + pos] = s;
    }
    __syncthreads();
    int lim = min(cnt, SEG_CAP);
    for (int i = tid; i < lim; i += 256) csr_src[r0 + i] = seg[i];
}

// ---------- FUSED layer-1 gather (dinv applied in-loop) + (hr @ W2)*dinv ----------
// h is UNSCALED bf16(x@W1); per-edge source weight dinv[s] comes from the 400 KB
// L2-resident dinv array (broadcast 4 B load, rides free under the 256 B row read).
__launch_bounds__(256)
__global__ void gather_gemm(const unsigned short* __restrict__ h,
                            const int* __restrict__ row_ptr,
                            const int* __restrict__ csr_src,
                            const float* __restrict__ dinv,
                            const float* __restrict__ bias1,
                            const unsigned short* __restrict__ WT2,
                            unsigned short* __restrict__ C2, int n) {
    constexpr int K  = HIDD;          // 128
    constexpr int KP = K + 8;         // 136
    constexpr int M2 = OUTD;          // 64
    __shared__ unsigned short Atl[16 * KP];     // 4.3 KB hr tile
    __shared__ unsigned short Wsl[M2 * KP];     // 17 KB W2^T

    const int tid = threadIdx.x;

    {
        constexpr int SEG = (K * 2) / 16;   // 16
        const uint4* srcp = (const uint4*)WT2;
        for (int idx = tid; idx < M2 * SEG; idx += 256) {
            int r = idx / SEG, s = idx - r * SEG;
            *(uint4*)(Wsl + r * KP + s * 8) = srcp[idx];
        }
    }

    const int g = tid >> 4;            // node within tile: 0..15
    const int l = tid & 15;            // feature slot: 0..15 (8 feats each)
    const int v0 = blockIdx.x * 16;
    const int v = v0 + g;

    uint4 pk = make_uint4(0u, 0u, 0u, 0u);
    if (v < n) {
        const float dv = dinv[v];
        float acc[8];
        {   // self-loop term: dinv[v] * h[v]
            uint4 u = *(const uint4*)(h + (size_t)v * K + l * 8);
            acc[0] = dv * bflo(u.x); acc[1] = dv * bfhi(u.x);
            acc[2] = dv * bflo(u.y); acc[3] = dv * bfhi(u.y);
            acc[4] = dv * bflo(u.z); acc[5] = dv * bfhi(u.z);
            acc[6] = dv * bflo(u.w); acc[7] = dv * bfhi(u.w);
        }

        int j   = row_ptr[v];
        int end = row_ptr[v + 1];
        for (; j + 3 < end; j += 4) {
            int s0 = csr_src[j];
            int s1 = csr_src[j + 1];
            int s2 = csr_src[j + 2];
            int s3 = csr_src[j + 3];
            float q0 = dinv[s0], q1 = dinv[s1], q2 = dinv[s2], q3 = dinv[s3];
            uint4 u0 = *(const uint4*)(h + (size_t)s0 * K + l * 8);
            uint4 u1 = *(const uint4*)(h + (size_t)s1 * K + l * 8);
            uint4 u2 = *(const uint4*)(h + (size_t)s2 * K + l * 8);
            uint4 u3 = *(const uint4*)(h + (size_t)s3 * K + l * 8);
            acc[0] += (q0 * bflo(u0.x) + q1 * bflo(u1.x)) + (q2 * bflo(u2.x) + q3 * bflo(u3.x));
            acc[1] += (q0 * bfhi(u0.x) + q1 * bfhi(u1.x)) + (q2 * bfhi(u2.x) + q3 * bfhi(u3.x));
            acc[2] += (q0 * bflo(u0.y) + q1 * bflo(u1.y)) + (q2 * bflo(u2.y) + q3 * bflo(u3.y));
            acc[3] += (q0 * bfhi(u0.y) + q1 * bfhi(u1.y)) + (q2 * bfhi(u2.y) + q3 * bfhi(u3.y));
            acc[4] += (q0 * bflo(u0.z) + q1 * bflo(u1.z)) + (q2 * bflo(u2.z) + q3 * bflo(u3.z));
            acc[5] += (q0 * bfhi(u0.z) + q1 * bfhi(u1.z)) + (q2 * bfhi(u2.z) + q3 * bfhi(u3.z));
            acc[6] += (q0 * bflo(u0.w) + q1 * bflo(u1.w)) + (q2 * bflo(u2.w) + q3 * bflo(u3.w));
            acc[7] += (q0 * bfhi(u0.w) + q1 * bfhi(u1.w)) + (q2 * bfhi(u2.w) + q3 * bfhi(u3.w));
        }
        for (; j < end; j++) {
            int s0 = csr_src[j];
            float q0 = dinv[s0];
            uint4 u0 = *(const uint4*)(h + (size_t)s0 * K + l * 8);
            acc[0] += q0 * bflo(u0.x); acc[1] += q0 * bfhi(u0.x);
            acc[2] += q0 * bflo(u0.y); acc[3] += q0 * bfhi(u0.y);
            acc[4] += q0 * bflo(u0.z); acc[5] += q0 * bfhi(u0.z);
            acc[6] += q0 * bflo(u0.w); acc[7] += q0 * bfhi(u0.w);
        }

#pragma unroll
        for (int i = 0; i < 8; i++) {
            acc[i] = fmaxf(acc[i] * dv + bias1[l * 8 + i], 0.0f);
        }
        pk.x = (uint32)f2bf(acc[0]) | ((uint32)f2bf(acc[1]) << 16);
        pk.y = (uint32)f2bf(acc[2]) | ((uint32)f2bf(acc[3]) << 16);
        pk.z = (uint32)f2bf(acc[4]) | ((uint32)f2bf(acc[5]) << 16);
        pk.w = (uint32)f2bf(acc[6]) | ((uint32)f2bf(acc[7]) << 16);
    }
    *(uint4*)(Atl + g * KP + l * 8) = pk;    // zero rows for v >= n
    __syncthreads();

    // MFMA: 16 nodes x 64 out-feats; wave wv owns column tile wv*16..wv*16+15
    const int lane = tid & 63;
    const int wv = tid >> 6;           // 0..3
    const int mm = lane & 15;
    const int qq = lane >> 4;

    floatx4 o = (floatx4){0.f, 0.f, 0.f, 0.f};
#pragma unroll
    for (int kc = 0; kc < K / 32; kc++) {
        short8 a = *(const short8*)(Atl + mm * KP + kc * 32 + qq * 8);
        short8 b = *(const short8*)(Wsl + (wv * 16 + mm) * KP + kc * 32 + qq * 8);
        o = __builtin_amdgcn_mfma_f32_16x16x32_bf16(a, b, o, 0, 0, 0);
    }

    // layer-2 table premultiplied by dinv (available now) -> gather_k unchanged
#pragma unroll
    for (int r = 0; r < 4; r++) {
        int grow = v0 + qq * 4 + r;
        if (grow < n) {
            float dv2 = dinv[grow];
            C2[(size_t)grow * M2 + wv * 16 + mm] = f2bf(o[r] * dv2);
        }
    }
}

// ---------- gather-aggregate over premultiplied bf16 table (node-major rows) ----------
template<int M, bool RELU, bool OBF16>
__launch_bounds__(256)
__global__ void gather_k(const unsigned short* __restrict__ h,
                         const int* __restrict__ row_ptr,
                         const int* __restrict__ csr_src,
                         const float* __restrict__ dinv,
                         const float* __restrict__ bias,
                         void* __restrict__ outp, int n) {
    constexpr int LPG = M / 8;
    constexpr int GPB = 256 / LPG;
    const int g = threadIdx.x / LPG;
    const int l = threadIdx.x % LPG;
    const int v = blockIdx.x * GPB + g;
    if (v >= n) return;

    const float dv = dinv[v];
    float acc[8];
    {
        uint4 u = *(const uint4*)(h + (size_t)v * M + l * 8);
        acc[0] = bflo(u.x); acc[1] = bfhi(u.x);
        acc[2] = bflo(u.y); acc[3] = bfhi(u.y);
        acc[4] = bflo(u.z); acc[5] = bfhi(u.z);
        acc[6] = bflo(u.w); acc[7] = bfhi(u.w);
    }

    int j   = row_ptr[v];
    int end = row_ptr[v + 1];
    for (; j + 3 < end; j += 4) {
        int s0 = csr_src[j];
        int s1 = csr_src[j + 1];
        int s2 = csr_src[j + 2];
        int s3 = csr_src[j + 3];
        uint4 u0 = *(const uint4*)(h + (size_t)s0 * M + l * 8);
        uint4 u1 = *(const uint4*)(h + (size_t)s1 * M + l * 8);
        uint4 u2 = *(const uint4*)(h + (size_t)s2 * M + l * 8);
        uint4 u3 = *(const uint4*)(h + (size_t)s3 * M + l * 8);
        acc[0] += (bflo(u0.x) + bflo(u1.x)) + (bflo(u2.x) + bflo(u3.x));
        acc[1] += (bfhi(u0.x) + bfhi(u1.x)) + (bfhi(u2.x) + bfhi(u3.x));
        acc[2] += (bflo(u0.y) + bflo(u1.y)) + (bflo(u2.y) + bflo(u3.y));
        acc[3] += (bfhi(u0.y) + bfhi(u1.y)) + (bfhi(u2.y) + bfhi(u3.y));
        acc[4] += (bflo(u0.z) + bflo(u1.z)) + (bflo(u2.z) + bflo(u3.z));
        acc[5] += (bfhi(u0.z) + bfhi(u1.z)) + (bfhi(u2.z) + bfhi(u3.z));
        acc[6] += (bflo(u0.w) + bflo(u1.w)) + (bflo(u2.w) + bflo(u3.w));
        acc[7] += (bfhi(u0.w) + bfhi(u1.w)) + (bfhi(u2.w) + bfhi(u3.w));
    }
    for (; j < end; j++) {
        int s0 = csr_src[j];
        uint4 u0 = *(const uint4*)(h + (size_t)s0 * M + l * 8);
        acc[0] += bflo(u0.x); acc[1] += bfhi(u0.x);
        acc[2] += bflo(u0.y); acc[3] += bfhi(u0.y);
        acc[4] += bflo(u0.z); acc[5] += bfhi(u0.z);
        acc[6] += bflo(u0.w); acc[7] += bfhi(u0.w);
    }

#pragma unroll
    for (int i = 0; i < 8; i++) {
        acc[i] = acc[i] * dv + bias[l * 8 + i];
        if (RELU) acc[i] = fmaxf(acc[i], 0.0f);
    }

    if constexpr (OBF16) {
        uivec4 p;
#pragma unroll
        for (int c = 0; c < 4; c++)
            p[c] = (uint32)f2bf(acc[2 * c]) | ((uint32)f2bf(acc[2 * c + 1]) << 16);
        __builtin_nontemporal_store(p,
            (uivec4*)((unsigned short*)outp + (size_t)v * M + l * 8));
    } else {
        float* op = (float*)outp + (size_t)v * M + l * 8;
        fvec4 a0 = {acc[0], acc[1], acc[2], acc[3]};
        fvec4 a1 = {acc[4], acc[5], acc[6], acc[7]};
        __builtin_nontemporal_store(a0, (fvec4*)op);
        __builtin_nontemporal_store(a1, (fvec4*)(op + 4));
    }
}

extern "C" void kernel_launch(void* const* d_in, const int* in_sizes, int n_in,
                              void* d_out, int out_size, void* d_ws, size_t ws_size,
                              hipStream_t stream) {
    const float* x  = (const float*)d_in[0];
    const float* W1 = (const float*)d_in[1];
    const float* b1 = (const float*)d_in[2];
    const float* W2 = (const float*)d_in[3];
    const float* b2 = (const float*)d_in[4];
    const int*   ei = (const int*)d_in[5];
    const int* src = ei;            // edge_index[0]
    const int* dst = ei + NEDGES;   // edge_index[1]
    float* out = (float*)d_out;

    // workspace layout (16B-aligned chunks):
    char* ws = (char*)d_ws;
    float*  dinv    = (float*)ws;   ws += (size_t)NNODES * 4;
    int*    row_ptr = (int*)ws;     ws += (size_t)(NNODES + 4) * 4;
    int*    bcnt    = (int*)ws;     ws += 512 * 4;
    unsigned short* wt2 = (unsigned short*)ws;  ws += (size_t)HIDD * OUTD * 2;
    int*    csr_src = (int*)ws;     ws += (size_t)NEDGES * 4;
    uint32* staging = (uint32*)ws;  ws += (size_t)NBUCK * SLACK * 4;   // 7.5 MB
    unsigned short* hbf1 = (unsigned short*)ws; ws += (size_t)NNODES * HIDD * 2;  // layer-1 bf16 table (unscaled)
    unsigned short* hbf2 = (unsigned short*)ws;                                    // layer-2 bf16 table (premult)

    // ---- merged: binning + layer-1 GEMM + W2 transpose (all independent) ----
    hipMemsetAsync(bcnt, 0, 512 * 4, stream);
    k_bin_gemm<<<BINB + GEMMB + WT2B, 512, 0, stream>>>(
        src, dst, bcnt, staging, NEDGES, x, W1, W2, wt2, hbf1, NNODES);

    // ---- CSR finalize -> row_ptr / csr_src / dinv ----
    k_fill3<<<NBUCK, 256, 0, stream>>>(staging, bcnt, row_ptr, csr_src, dinv, NNODES);

    // ---- fused: gather1 (dinv-in-loop, +b1, ReLU) -> @W2 -> *dinv -> hbf2(bf16) ----
    gather_gemm<<<(NNODES + 15) / 16, 256, 0, stream>>>(
        hbf1, row_ptr, csr_src, dinv, b1, wt2, hbf2, NNODES);

    // ---- layer 2 gather: out(f32) = gather(hbf2)*dv + b2 ----
    gather_k<OUTD, false, false><<<(NNODES * (OUTD / 8) + 255) / 256, 256, 0, stream>>>(
        hbf2, row_ptr, csr_src, dinv, b2, out, NNODES);
}

// Round 13
// 273.902 us; speedup vs baseline: 1.1031x; 1.0208x over previous
//
#include <hip/hip_runtime.h>

#define NNODES 100000
#define NEDGES 1600000
#define IND 128
#define HIDD 128
#define OUTD 64

// bucketed CSR build: 256-node buckets
#define BSHIFT 8
#define BSIZE  256
#define NBUCK  ((NNODES + BSIZE - 1) / BSIZE)        // 391
#define SLACK  4800                                  // mean 4092 + 11 sigma
#define SEG_CAP 5120
#define BIN_EPB 8192
#define BINB   ((NEDGES + BIN_EPB - 1) / BIN_EPB)    // 196
#define GEMMB  ((NNODES + 127) / 128)                // 782
#define WT2B   ((HIDD * OUTD + 511) / 512)           // 16

typedef unsigned int  uint32;
typedef __attribute__((ext_vector_type(8))) short short8;
typedef __attribute__((ext_vector_type(4))) float floatx4;
typedef __attribute__((ext_vector_type(4))) unsigned int uivec4;
typedef __attribute__((ext_vector_type(4))) float fvec4;

// ---------- bf16 helpers ----------
__device__ __forceinline__ unsigned short f2bf(float f) {
    union { float f; uint32 u; } x; x.f = f;
    uint32 u = x.u;
    return (unsigned short)((u + 0x7fffu + ((u >> 16) & 1u)) >> 16);   // RNE
}
__device__ __forceinline__ float bflo(uint32 u) {
    union { uint32 i; float f; } x; x.i = u << 16; return x.f;
}
__device__ __forceinline__ float bfhi(uint32 u) {
    union { uint32 i; float f; } x; x.i = u & 0xffff0000u; return x.f;
}

// ---------- merged dispatch 1: edge binning (LDS counting sort) + layer-1 GEMM + W2 transpose ----------
// Binning blocks [0, BINB): 512 threads x 16 register-held edges. Edges are sorted
// by bucket INSIDE LDS first (ent/bkt arrays), then copied out as contiguous runs:
// consecutive lanes -> consecutive staging addresses. Kills the 9x write amp of the
// random global scatter (round-7 PMC: 57.5 MB written for 6.4 MB payload) and removes
// the per-edge global-latency chain.
// GEMM blocks [BINB, BINB+GEMMB): C1[n x 128](bf16, UNSCALED) = x @ W1 (no CSR dep).
// Tail [BINB+GEMMB, +WT2B): W2 transpose.
__launch_bounds__(512)
__global__ void k_bin_gemm(const int* __restrict__ src, const int* __restrict__ dst,
                           int* __restrict__ bcnt, uint32* __restrict__ staging, int e,
                           const float* __restrict__ x, const float* __restrict__ W1,
                           const float* __restrict__ W2, unsigned short* __restrict__ wt2,
                           unsigned short* __restrict__ C, int n) {
    constexpr int K = IND;            // 128
    constexpr int KP = K + 8;         // 136
    constexpr int M = HIDD;           // 128
    constexpr int NT = M / 16;
    __shared__ __align__(16) char smem[2 * 128 * KP * 2];   // 69632 B (union of branches)

    const int tid = threadIdx.x;
    const int bid = blockIdx.x;

    if (bid < BINB) {
        int* lh     = (int*)smem;                 // [NBUCK]
        int* lstart = lh + NBUCK;                 // [NBUCK]
        int* lcur   = lstart + NBUCK;             // [NBUCK]
        int* gres   = lcur + NBUCK;               // [NBUCK]
        int* sbuf   = gres + NBUCK;               // [512]
        uint32* ent = (uint32*)(sbuf + 512);      // [BIN_EPB] 32 KB
        unsigned short* bkt = (unsigned short*)(ent + BIN_EPB);  // [BIN_EPB] 16 KB
        // total ~57 KB < 69632

        for (int i = tid; i < NBUCK; i += 512) lh[i] = 0;
        __syncthreads();

        const int start = bid * BIN_EPB;
        const int end = min(start + BIN_EPB, e);
        const int4* d4 = (const int4*)dst;
        const int4* s4 = (const int4*)src;

        int4 dv[4], sv[4];
        bool val[4];
#pragma unroll
        for (int k = 0; k < 4; k++) {
            int off = start + 4 * (k * 512 + tid);   // e % 4 == 0: whole int4 valid or none
            val[k] = off < e;
            if (val[k]) { dv[k] = d4[off >> 2]; sv[k] = s4[off >> 2]; }
        }

#pragma unroll
        for (int k = 0; k < 4; k++) {
            if (val[k]) {
                atomicAdd(&lh[dv[k].x >> BSHIFT], 1);
                atomicAdd(&lh[dv[k].y >> BSHIFT], 1);
                atomicAdd(&lh[dv[k].z >> BSHIFT], 1);
                atomicAdd(&lh[dv[k].w >> BSHIFT], 1);
            }
        }
        __syncthreads();

        // 512-wide exclusive scan of lh -> block-local run starts; global reservation
        int vb = (tid < NBUCK) ? lh[tid] : 0;
        sbuf[tid] = vb;
        __syncthreads();
        for (int off = 1; off < 512; off <<= 1) {
            int t = (tid >= off) ? sbuf[tid - off] : 0;
            __syncthreads();
            sbuf[tid] += t;
            __syncthreads();
        }
        if (tid < NBUCK) {
            int ex = sbuf[tid] - vb;
            lstart[tid] = ex;
            lcur[tid]   = ex;
            gres[tid]   = vb ? atomicAdd(&bcnt[tid], vb) : 0;
        }
        __syncthreads();

        // scatter into LDS (bucket-ordered)
#pragma unroll
        for (int k = 0; k < 4; k++) {
            if (val[k]) {
                int d, s, b, pos;
                d = dv[k].x; s = sv[k].x; b = d >> BSHIFT;
                pos = atomicAdd(&lcur[b], 1);
                ent[pos] = ((uint32)(d & (BSIZE - 1)) << 17) | (uint32)s;
                bkt[pos] = (unsigned short)b;
                d = dv[k].y; s = sv[k].y; b = d >> BSHIFT;
                pos = atomicAdd(&lcur[b], 1);
                ent[pos] = ((uint32)(d & (BSIZE - 1)) << 17) | (uint32)s;
                bkt[pos] = (unsigned short)b;
                d = dv[k].z; s = sv[k].z; b = d >> BSHIFT;
                pos = atomicAdd(&lcur[b], 1);
                ent[pos] = ((uint32)(d & (BSIZE - 1)) << 17) | (uint32)s;
                bkt[pos] = (unsigned short)b;
                d = dv[k].w; s = sv[k].w; b = d >> BSHIFT;
                pos = atomicAdd(&lcur[b], 1);
                ent[pos] = ((uint32)(d & (BSIZE - 1)) << 17) | (uint32)s;
                bkt[pos] = (unsigned short)b;
            }
        }
        __syncthreads();

        // streaming copy-out: consecutive lanes -> consecutive staging addresses
        const int total = end - start;
        for (int i = tid; i < total; i += 512) {
            int b = bkt[i];
            int p = gres[b] + (i - lstart[b]);
            if (p < SLACK)
                staging[(size_t)b * SLACK + p] = ent[i];
        }
        return;
    }

    if (bid >= BINB + GEMMB) {
        // W2 transpose
        int idx = (bid - BINB - GEMMB) * 512 + tid;
        if (idx < HIDD * OUTD) {
            int k = idx / OUTD, m = idx - k * OUTD;
            wt2[m * HIDD + k] = f2bf(W2[idx]);
        }
        return;
    }

    // ---- layer-1 GEMM branch: C = bf16(x @ W1), unscaled ----
    unsigned short* Asl = (unsigned short*)smem;       // 128 x KP
    unsigned short* Wsl = Asl + 128 * KP;              // 128 x KP

    const int row0 = (bid - BINB) * 128;

    // W1 in-kernel transpose-stage: W1[k][m] (row-major) -> Wsl[m*KP + k]
    for (int idx = tid; idx < 128 * 128; idx += 512) {
        int k = idx >> 7, m = idx & 127;               // coalesced read over m
        Wsl[m * KP + k] = f2bf(W1[idx]);
    }
    {
        constexpr int F4R = K / 4;
        for (int idx = tid; idx < 128 * F4R; idx += 512) {
            int r = idx / F4R, s = idx - r * F4R;
            int grow = row0 + r; if (grow >= n) grow = n - 1;
            float4 v = *(const float4*)(x + (size_t)grow * K + s * 4);
            uint32 p0 = (uint32)f2bf(v.x) | ((uint32)f2bf(v.y) << 16);
            uint32 p1 = (uint32)f2bf(v.z) | ((uint32)f2bf(v.w) << 16);
            *(uint2*)(Asl + r * KP + s * 4) = make_uint2(p0, p1);
        }
    }
    __syncthreads();

    const int lane = tid & 63;
    const int wave = tid >> 6;
    const int mm = lane & 15;
    const int qq = lane >> 4;

    floatx4 acc[NT];
#pragma unroll
    for (int t = 0; t < NT; t++) acc[t] = (floatx4){0.f, 0.f, 0.f, 0.f};

#pragma unroll
    for (int kc = 0; kc < K / 32; kc++) {
        short8 a = *(const short8*)(Asl + (wave * 16 + mm) * KP + kc * 32 + qq * 8);
#pragma unroll
        for (int t = 0; t < NT; t++) {
            short8 b = *(const short8*)(Wsl + (t * 16 + mm) * KP + kc * 32 + qq * 8);
            acc[t] = __builtin_amdgcn_mfma_f32_16x16x32_bf16(a, b, acc[t], 0, 0, 0);
        }
    }

#pragma unroll
    for (int r = 0; r < 4; r++) {
        int grow = row0 + wave * 16 + qq * 4 + r;
        if (grow < n) {
#pragma unroll
            for (int t = 0; t < NT; t++)
                C[(size_t)grow * M + t * 16 + mm] = f2bf(acc[t][r]);
        }
    }
}

// ---------- phase C: per-bucket CSR finalize (256 nodes/bucket, one node/thread) ----------
__global__ __launch_bounds__(256)
void k_fill3(const uint32* __restrict__ staging, const int* __restrict__ bcnt,
             int* __restrict__ row_ptr, int* __restrict__ csr_src,
             float* __restrict__ dinv, int n) {
    __shared__ int nc[BSIZE];
    __shared__ int lcur[BSIZE];
    __shared__ int red[256];
    __shared__ int wsum[4];
    __shared__ int seg[SEG_CAP];    // 20 KB
    const int b = blockIdx.x;
    const int base = b << BSHIFT;
    const int tid = threadIdx.x;

    nc[tid] = 0;

    // r0 = sum of bucket counts below b (reduction, not scan)
    int t0 = (tid < b) ? bcnt[tid] : 0;
    int t1 = (tid + 256 < b) ? bcnt[tid + 256] : 0;
    red[tid] = t0 + t1;
    __syncthreads();
    for (int off = 128; off > 0; off >>= 1) {
        if (tid < off) red[tid] += red[tid + off];
        __syncthreads();
    }
    const int r0 = red[0];

    const uint32* st = staging + (size_t)b * SLACK;
    const int cnt = bcnt[b];
    for (int i = tid; i < cnt; i += 256)
        atomicAdd(&nc[st[i] >> 17], 1);
    __syncthreads();

    // per-node exclusive offsets: wave-shuffle inclusive scan over 256
    const int lane = tid & 63;
    const int w = tid >> 6;
    int dg = nc[tid];
    int v = dg;
#pragma unroll
    for (int off = 1; off < 64; off <<= 1) {
        int t = __shfl_up(v, off);
        if (lane >= off) v += t;
    }
    if (lane == 63) wsum[w] = v;
    __syncthreads();
    if (tid == 0) {
        int a = 0;
#pragma unroll
        for (int i = 0; i < 4; i++) { int t = wsum[i]; wsum[i] = a; a += t; }
    }
    __syncthreads();
    const int inc = v + wsum[w];     // inclusive prefix
    const int ex = inc - dg;
    const int vnode = base + tid;
    if (vnode < n) {
        row_ptr[vnode] = r0 + ex;
        dinv[vnode] = rsqrtf((float)(dg + 1));
    }
    lcur[tid] = ex;
    if (b == NBUCK - 1 && tid == 255) row_ptr[n] = r0 + inc;   // inc@255 == cnt
    __syncthreads();

    for (int i = tid; i < cnt; i += 256) {
        uint32 p = st[i];
        int dl = (int)(p >> 17);
        int s  = (int)(p & 0x1FFFFu);
        int pos = atomicAdd(&lcur[dl], 1);
        if (pos < SEG_CAP) seg[pos] = s;
        else               csr_src[r0 + pos] = s;
    }
    __syncthreads();
    int lim = min(cnt, SEG_CAP);
    for (int i = tid; i < lim; i += 256) csr_src[r0 + i] = seg[i];
}

// ---------- FUSED layer-1 gather (dinv applied in-loop) + (hr @ W2)*dinv ----------
// h is UNSCALED bf16(x@W1); per-edge source weight dinv[s] comes from the 400 KB
// L2-resident dinv array (broadcast 4 B load, rides free under the 256 B row read).
__launch_bounds__(256)
__global__ void gather_gemm(const unsigned short* __restrict__ h,
                            const int* __restrict__ row_ptr,
                            const int* __restrict__ csr_src,
                            const float* __restrict__ dinv,
                            const float* __restrict__ bias1,
                            const unsigned short* __restrict__ WT2,
                            unsigned short* __restrict__ C2, int n) {
    constexpr int K  = HIDD;          // 128
    constexpr int KP = K + 8;         // 136
    constexpr int M2 = OUTD;          // 64
    __shared__ unsigned short Atl[16 * KP];     // 4.3 KB hr tile
    __shared__ unsigned short Wsl[M2 * KP];     // 17 KB W2^T

    const int tid = threadIdx.x;

    {
        constexpr int SEG = (K * 2) / 16;   // 16
        const uint4* srcp = (const uint4*)WT2;
        for (int idx = tid; idx < M2 * SEG; idx += 256) {
            int r = idx / SEG, s = idx - r * SEG;
            *(uint4*)(Wsl + r * KP + s * 8) = srcp[idx];
        }
    }

    const int g = tid >> 4;            // node within tile: 0..15
    const int l = tid & 15;            // feature slot: 0..15 (8 feats each)
    const int v0 = blockIdx.x * 16;
    const int v = v0 + g;

    uint4 pk = make_uint4(0u, 0u, 0u, 0u);
    if (v < n) {
        const float dv = dinv[v];
        float acc[8];
        {   // self-loop term: dinv[v] * h[v]
            uint4 u = *(const uint4*)(h + (size_t)v * K + l * 8);
            acc[0] = dv * bflo(u.x); acc[1] = dv * bfhi(u.x);
            acc[2] = dv * bflo(u.y); acc[3] = dv * bfhi(u.y);
            acc[4] = dv * bflo(u.z); acc[5] = dv * bfhi(u.z);
            acc[6] = dv * bflo(u.w); acc[7] = dv * bfhi(u.w);
        }

        int j   = row_ptr[v];
        int end = row_ptr[v + 1];
        for (; j + 3 < end; j += 4) {
            int s0 = csr_src[j];
            int s1 = csr_src[j + 1];
            int s2 = csr_src[j + 2];
            int s3 = csr_src[j + 3];
            float q0 = dinv[s0], q1 = dinv[s1], q2 = dinv[s2], q3 = dinv[s3];
            uint4 u0 = *(const uint4*)(h + (size_t)s0 * K + l * 8);
            uint4 u1 = *(const uint4*)(h + (size_t)s1 * K + l * 8);
            uint4 u2 = *(const uint4*)(h + (size_t)s2 * K + l * 8);
            uint4 u3 = *(const uint4*)(h + (size_t)s3 * K + l * 8);
            acc[0] += (q0 * bflo(u0.x) + q1 * bflo(u1.x)) + (q2 * bflo(u2.x) + q3 * bflo(u3.x));
            acc[1] += (q0 * bfhi(u0.x) + q1 * bfhi(u1.x)) + (q2 * bfhi(u2.x) + q3 * bfhi(u3.x));
            acc[2] += (q0 * bflo(u0.y) + q1 * bflo(u1.y)) + (q2 * bflo(u2.y) + q3 * bflo(u3.y));
            acc[3] += (q0 * bfhi(u0.y) + q1 * bfhi(u1.y)) + (q2 * bfhi(u2.y) + q3 * bfhi(u3.y));
            acc[4] += (q0 * bflo(u0.z) + q1 * bflo(u1.z)) + (q2 * bflo(u2.z) + q3 * bflo(u3.z));
            acc[5] += (q0 * bfhi(u0.z) + q1 * bfhi(u1.z)) + (q2 * bfhi(u2.z) + q3 * bfhi(u3.z));
            acc[6] += (q0 * bflo(u0.w) + q1 * bflo(u1.w)) + (q2 * bflo(u2.w) + q3 * bflo(u3.w));
            acc[7] += (q0 * bfhi(u0.w) + q1 * bfhi(u1.w)) + (q2 * bfhi(u2.w) + q3 * bfhi(u3.w));
        }
        for (; j < end; j++) {
            int s0 = csr_src[j];
            float q0 = dinv[s0];
            uint4 u0 = *(const uint4*)(h + (size_t)s0 * K + l * 8);
            acc[0] += q0 * bflo(u0.x); acc[1] += q0 * bfhi(u0.x);
            acc[2] += q0 * bflo(u0.y); acc[3] += q0 * bfhi(u0.y);
            acc[4] += q0 * bflo(u0.z); acc[5] += q0 * bfhi(u0.z);
            acc[6] += q0 * bflo(u0.w); acc[7] += q0 * bfhi(u0.w);
        }

#pragma unroll
        for (int i = 0; i < 8; i++) {
            acc[i] = fmaxf(acc[i] * dv + bias1[l * 8 + i], 0.0f);
        }
        pk.x = (uint32)f2bf(acc[0]) | ((uint32)f2bf(acc[1]) << 16);
        pk.y = (uint32)f2bf(acc[2]) | ((uint32)f2bf(acc[3]) << 16);
        pk.z = (uint32)f2bf(acc[4]) | ((uint32)f2bf(acc[5]) << 16);
        pk.w = (uint32)f2bf(acc[6]) | ((uint32)f2bf(acc[7]) << 16);
    }
    *(uint4*)(Atl + g * KP + l * 8) = pk;    // zero rows for v >= n
    __syncthreads();

    // MFMA: 16 nodes x 64 out-feats; wave wv owns column tile wv*16..wv*16+15
    const int lane = tid & 63;
    const int wv = tid >> 6;           // 0..3
    const int mm = lane & 15;
    const int qq = lane >> 4;

    floatx4 o = (floatx4){0.f, 0.f, 0.f, 0.f};
#pragma unroll
    for (int kc = 0; kc < K / 32; kc++) {
        short8 a = *(const short8*)(Atl + mm * KP + kc * 32 + qq * 8);
        short8 b = *(const short8*)(Wsl + (wv * 16 + mm) * KP + kc * 32 + qq * 8);
        o = __builtin_amdgcn_mfma_f32_16x16x32_bf16(a, b, o, 0, 0, 0);
    }

    // layer-2 table premultiplied by dinv (available now) -> gather_k unchanged
#pragma unroll
    for (int r = 0; r < 4; r++) {
        int grow = v0 + qq * 4 + r;
        if (grow < n) {
            float dv2 = dinv[grow];
            C2[(size_t)grow * M2 + wv * 16 + mm] = f2bf(o[r] * dv2);
        }
    }
}

// ---------- gather-aggregate over premultiplied bf16 table (node-major rows) ----------
template<int M, bool RELU, bool OBF16>
__launch_bounds__(256)
__global__ void gather_k(const unsigned short* __restrict__ h,
                         const int* __restrict__ row_ptr,
                         const int* __restrict__ csr_src,
                         const float* __restrict__ dinv,
                         const float* __restrict__ bias,
                         void* __restrict__ outp, int n) {
    constexpr int LPG = M / 8;
    constexpr int GPB = 256 / LPG;
    const int g = threadIdx.x / LPG;
    const int l = threadIdx.x % LPG;
    const int v = blockIdx.x * GPB + g;
    if (v >= n) return;

    const float dv = dinv[v];
    float acc[8];
    {
        uint4 u = *(const uint4*)(h + (size_t)v * M + l * 8);
        acc[0] = bflo(u.x); acc[1] = bfhi(u.x);
        acc[2] = bflo(u.y); acc[3] = bfhi(u.y);
        acc[4] = bflo(u.z); acc[5] = bfhi(u.z);
        acc[6] = bflo(u.w); acc[7] = bfhi(u.w);
    }

    int j   = row_ptr[v];
    int end = row_ptr[v + 1];
    for (; j + 3 < end; j += 4) {
        int s0 = csr_src[j];
        int s1 = csr_src[j + 1];
        int s2 = csr_src[j + 2];
        int s3 = csr_src[j + 3];
        uint4 u0 = *(const uint4*)(h + (size_t)s0 * M + l * 8);
        uint4 u1 = *(const uint4*)(h + (size_t)s1 * M + l * 8);
        uint4 u2 = *(const uint4*)(h + (size_t)s2 * M + l * 8);
        uint4 u3 = *(const uint4*)(h + (size_t)s3 * M + l * 8);
        acc[0] += (bflo(u0.x) + bflo(u1.x)) + (bflo(u2.x) + bflo(u3.x));
        acc[1] += (bfhi(u0.x) + bfhi(u1.x)) + (bfhi(u2.x) + bfhi(u3.x));
        acc[2] += (bflo(u0.y) + bflo(u1.y)) + (bflo(u2.y) + bflo(u3.y));
        acc[3] += (bfhi(u0.y) + bfhi(u1.y)) + (bfhi(u2.y) + bfhi(u3.y));
        acc[4] += (bflo(u0.z) + bflo(u1.z)) + (bflo(u2.z) + bflo(u3.z));
        acc[5] += (bfhi(u0.z) + bfhi(u1.z)) + (bfhi(u2.z) + bfhi(u3.z));
        acc[6] += (bflo(u0.w) + bflo(u1.w)) + (bflo(u2.w) + bflo(u3.w));
        acc[7] += (bfhi(u0.w) + bfhi(u1.w)) + (bfhi(u2.w) + bfhi(u3.w));
    }
    for (; j < end; j++) {
        int s0 = csr_src[j];
        uint4 u0 = *(const uint4*)(h + (size_t)s0 * M + l * 8);
        acc[0] += bflo(u0.x); acc[1] += bfhi(u0.x);
        acc[2] += bflo(u0.y); acc[3] += bfhi(u0.y);
        acc[4] += bflo(u0.z); acc[5] += bfhi(u0.z);
        acc[6] += bflo(u0.w); acc[7] += bfhi(u0.w);
    }

#pragma unroll
    for (int i = 0; i < 8; i++) {
        acc[i] = acc[i] * dv + bias[l * 8 + i];
        if (RELU) acc[i] = fmaxf(acc[i], 0.0f);
    }

    if constexpr (OBF16) {
        uivec4 p;
#pragma unroll
        for (int c = 0; c < 4; c++)
            p[c] = (uint32)f2bf(acc[2 * c]) | ((uint32)f2bf(acc[2 * c + 1]) << 16);
        __builtin_nontemporal_store(p,
            (uivec4*)((unsigned short*)outp + (size_t)v * M + l * 8));
    } else {
        float* op = (float*)outp + (size_t)v * M + l * 8;
        fvec4 a0 = {acc[0], acc[1], acc[2], acc[3]};
        fvec4 a1 = {acc[4], acc[5], acc[6], acc[7]};
        __builtin_nontemporal_store(a0, (fvec4*)op);
        __builtin_nontemporal_store(a1, (fvec4*)(op + 4));
    }
}

extern "C" void kernel_launch(void* const* d_in, const int* in_sizes, int n_in,
                              void* d_out, int out_size, void* d_ws, size_t ws_size,
                              hipStream_t stream) {
    const float* x  = (const float*)d_in[0];
    const float* W1 = (const float*)d_in[1];
    const float* b1 = (const float*)d_in[2];
    const float* W2 = (const float*)d_in[3];
    const float* b2 = (const float*)d_in[4];
    const int*   ei = (const int*)d_in[5];
    const int* src = ei;            // edge_index[0]
    const int* dst = ei + NEDGES;   // edge_index[1]
    float* out = (float*)d_out;

    // workspace layout (16B-aligned chunks):
    char* ws = (char*)d_ws;
    float*  dinv    = (float*)ws;   ws += (size_t)NNODES * 4;
    int*    row_ptr = (int*)ws;     ws += (size_t)(NNODES + 4) * 4;
    int*    bcnt    = (int*)ws;     ws += 512 * 4;
    unsigned short* wt2 = (unsigned short*)ws;  ws += (size_t)HIDD * OUTD * 2;
    int*    csr_src = (int*)ws;     ws += (size_t)NEDGES * 4;
    uint32* staging = (uint32*)ws;  ws += (size_t)NBUCK * SLACK * 4;   // 7.5 MB
    unsigned short* hbf1 = (unsigned short*)ws; ws += (size_t)NNODES * HIDD * 2;  // layer-1 bf16 table (unscaled)
    unsigned short* hbf2 = (unsigned short*)ws;                                    // layer-2 bf16 table (premult)

    // ---- merged: binning + layer-1 GEMM + W2 transpose (all independent) ----
    hipMemsetAsync(bcnt, 0, 512 * 4, stream);
    k_bin_gemm<<<BINB + GEMMB + WT2B, 512, 0, stream>>>(
        src, dst, bcnt, staging, NEDGES, x, W1, W2, wt2, hbf1, NNODES);

    // ---- CSR finalize -> row_ptr / csr_src / dinv ----
    k_fill3<<<NBUCK, 256, 0, stream>>>(staging, bcnt, row_ptr, csr_src, dinv, NNODES);

    // ---- fused: gather1 (dinv-in-loop, +b1, ReLU) -> @W2 -> *dinv -> hbf2(bf16) ----
    gather_gemm<<<(NNODES + 15) / 16, 256, 0, stream>>>(
        hbf1, row_ptr, csr_src, dinv, b1, wt2, hbf2, NNODES);

    // ---- layer 2 gather: out(f32) = gather(hbf2)*dv + b2 ----
    gather_k<OUTD, false, false><<<(NNODES * (OUTD / 8) + 255) / 256, 256, 0, stream>>>(
        hbf2, row_ptr, csr_src, dinv, b2, out, NNODES);
}